// Round 2
// baseline (670.588 us; speedup 1.0000x reference)
//
#include <hip/hip_runtime.h>

#define ANUM 5
#define EPS 1e-10f

// ---------------------------------------------------------------------------
// Precompute kernel. Cayley: Q = (I-Bm)^{-1}(I+Bm), Bm = L - L^T,
// L[i+1][c] = bias[i+c] (c<=i). Emits GATE-SCALED matrices so the main loop
// is 5 fully independent congruence transforms:
//   Ph = Qt' X Qt'^T + Q1' Yt Q1'^T            (Qt'=sqrt(1-t)Qt, Q1'=sqrt(t)QtQr)
//   Ot = Qy S0 Qy^T + Q2' X Q2'^T + Q3' Yt Q3'^T
//        (S0 = sum ks_a(1-a_a)M_a,  Q2'=sqrt(c(1-t))QyQt, Q3'=sqrt(ct)QyQtQr,
//         c = sum ks_a a_a;  since St = S0 + c*Ph)
// ws layout: [0..63]=Qt' [64..127]=Q1' [128..191]=Qy [192..255]=Q2'
//            [256..319]=Q3' [320..324]=w_r [325..329]=ks*(1-alpha)
// ---------------------------------------------------------------------------
__global__ void precompute_kernel(const float* __restrict__ kernel_r,
                                  const float* __restrict__ kernel_t,
                                  const float* __restrict__ kernel_phi,
                                  const float* __restrict__ kernel_s,
                                  const float* __restrict__ bias_r,
                                  const float* __restrict__ bias_t,
                                  const float* __restrict__ bias_y,
                                  float* __restrict__ ws) {
  __shared__ float sQ[4][64];  // Qr, Qt, Qy, Q1
  const int tid = threadIdx.x;
  if (tid < 3) {
    const float* bias = (tid == 0) ? bias_r : (tid == 1) ? bias_t : bias_y;

    float Bm[8][8];
#pragma unroll
    for (int a = 0; a < 8; ++a)
#pragma unroll
      for (int b = 0; b < 8; ++b) Bm[a][b] = 0.f;
#pragma unroll
    for (int a = 0; a < 7; ++a) {
#pragma unroll 8
      for (int c = 0; c < 7; ++c) {
        if (c <= a) {
          float v = bias[a + c];
          Bm[a + 1][c] = v;   // strictly lower
          Bm[c][a + 1] = -v;  // strictly upper
        }
      }
    }
    float A[8][8], C[8][8];
#pragma unroll
    for (int a = 0; a < 8; ++a)
#pragma unroll
      for (int b = 0; b < 8; ++b) {
        float id = (a == b) ? 1.f : 0.f;
        A[a][b] = id - Bm[a][b];
        C[a][b] = id + Bm[a][b];
      }
    // Gauss-Jordan (no pivoting: I - Bm has symmetric part I, stable)
#pragma unroll
    for (int p = 0; p < 8; ++p) {
      float inv = 1.f / A[p][p];
#pragma unroll
      for (int b = 0; b < 8; ++b) { A[p][b] *= inv; C[p][b] *= inv; }
#pragma unroll
      for (int r = 0; r < 8; ++r) {
        if (r == p) continue;
        float f = A[r][p];
#pragma unroll
        for (int b = 0; b < 8; ++b) { A[r][b] -= f * A[p][b]; C[r][b] -= f * C[p][b]; }
      }
    }
#pragma unroll
    for (int a = 0; a < 8; ++a)
#pragma unroll
      for (int b = 0; b < 8; ++b) sQ[tid][a * 8 + b] = C[a][b];
  }
  __syncthreads();
  const int i = tid >> 3, j = tid & 7;
  // Q1 = Qt @ Qr
  float q1 = 0.f;
#pragma unroll
  for (int k = 0; k < 8; ++k) q1 += sQ[1][i * 8 + k] * sQ[0][k * 8 + j];
  sQ[3][tid] = q1;
  __syncthreads();
  // Q2 = Qy @ Qt,  Q3 = Qy @ Q1
  float q2 = 0.f, q3 = 0.f;
#pragma unroll
  for (int k = 0; k < 8; ++k) {
    q2 += sQ[2][i * 8 + k] * sQ[1][k * 8 + j];
    q3 += sQ[2][i * 8 + k] * sQ[3][k * 8 + j];
  }
  // scalar gates (all lanes compute redundantly)
  float sr = 0.f, ss = 0.f;
#pragma unroll
  for (int a = 0; a < ANUM; ++a) sr += kernel_r[a] * kernel_r[a];
#pragma unroll
  for (int a = 0; a < ANUM; ++a) ss += kernel_s[a] * kernel_s[a];
  const float alpha[ANUM] = {0.01f, 0.25f, 0.5f, 0.9f, 0.99f};
  float c = 0.f;
#pragma unroll
  for (int a = 0; a < ANUM; ++a)
    c += (kernel_s[a] * kernel_s[a] / (ss + EPS)) * alpha[a];
  float kt2 = kernel_t[0] * kernel_t[0];
  float kp2 = kernel_phi[0] * kernel_phi[0];
  float t = kt2 / (kt2 + kp2 + EPS);

  const float s1 = sqrtf(1.f - t);
  const float s2 = sqrtf(t);
  const float s3 = sqrtf(c * (1.f - t));
  const float s4 = sqrtf(c * t);

  ws[tid]        = sQ[1][tid] * s1;  // Qt'
  ws[64 + tid]   = sQ[3][tid] * s2;  // Q1'
  ws[128 + tid]  = sQ[2][tid];       // Qy
  ws[192 + tid]  = q2 * s3;          // Q2'
  ws[256 + tid]  = q3 * s4;          // Q3'
  if (tid < ANUM) {
    ws[320 + tid] = kernel_r[tid] * kernel_r[tid] / (sr + EPS);
    ws[325 + tid] = (kernel_s[tid] * kernel_s[tid] / (ss + EPS)) * (1.f - alpha[tid]);
  }
}

// ---------------------------------------------------------------------------
// Main kernel: one wave per batch element, lane = i*8+j. Wave-synchronous
// LDS (private buffer per wave, no __syncthreads). All 5 congruence
// transforms are independent -> a single write/read/write/read LDS round
// (2 lgkm waits per iteration) with 5-way ILP, and next-element global
// loads stay in flight underneath (no barrier ever drains vmcnt).
// ---------------------------------------------------------------------------
__device__ __forceinline__ float dot8(float4 a0, float4 a1, float4 b0, float4 b1) {
  return a0.x * b0.x + a0.y * b0.y + a0.z * b0.z + a0.w * b0.w +
         a1.x * b1.x + a1.y * b1.y + a1.z * b1.z + a1.w * b1.w;
}

#define LGKM0() asm volatile("s_waitcnt lgkmcnt(0)" ::: "memory")
#define UNI(nm, idx) \
  const float nm = __int_as_float(__builtin_amdgcn_readfirstlane(__float_as_int(ws[idx])));

__launch_bounds__(256)
__global__ void spdsru_kernel(const float* __restrict__ x,
                              const float* __restrict__ states,
                              const float* __restrict__ ws,
                              float* __restrict__ out,        // B*64
                              float* __restrict__ out_state,  // B*320
                              int B, int ITER, int W) {
  __shared__ __align__(16) float lds[4][5][64];
  const int tid = threadIdx.x;
  const int lane = tid & 63;
  const int wv = tid >> 6;
  const int i = lane >> 3, j = lane & 7;
  float* bX = lds[wv][0];
  float* bY = lds[wv][1];
  float* bS = lds[wv][2];
  float* b3 = lds[wv][3];
  float* b4 = lds[wv][4];

  // Q rows -> registers (loop-invariant; 20 float4 = 80 VGPRs)
#define LOADQ(nm, off)                                          \
  const float4 nm##i0 = *(const float4*)(ws + off + i * 8);     \
  const float4 nm##i1 = *(const float4*)(ws + off + i * 8 + 4); \
  const float4 nm##j0 = *(const float4*)(ws + off + j * 8);     \
  const float4 nm##j1 = *(const float4*)(ws + off + j * 8 + 4);
  LOADQ(Qt, 0)
  LOADQ(Q1, 64)
  LOADQ(Qy, 128)
  LOADQ(Q2, 192)
  LOADQ(Q3, 256)
#undef LOADQ

  // uniform weights -> SGPRs (readfirstlane keeps them off the VGPR budget)
  UNI(wr0, 320) UNI(wr1, 321) UNI(wr2, 322) UNI(wr3, 323) UNI(wr4, 324)
  UNI(w20, 325) UNI(w21, 326) UNI(w22, 327) UNI(w23, 328) UNI(w24, 329)

  const int wave = (blockIdx.x * 256 + tid) >> 6;

  int b = wave;
  float X = 0.f, M0 = 0.f, M1 = 0.f, M2 = 0.f, M3 = 0.f, M4 = 0.f;
  if (b < B) {
    const float* S = states + (size_t)b * 320;
    X  = x[(size_t)b * 64 + lane];
    M0 = S[0 * 64 + lane];
    M1 = S[1 * 64 + lane];
    M2 = S[2 * 64 + lane];
    M3 = S[3 * 64 + lane];
    M4 = S[4 * 64 + lane];
  }

  for (int it = 0; it < ITER; ++it) {
    const int bn = b + W;
    // ---- prefetch next element (no barriers anywhere: stays in flight) ----
    float Xn = 0.f, N0 = 0.f, N1 = 0.f, N2 = 0.f, N3 = 0.f, N4 = 0.f;
    if (it + 1 < ITER && bn < B) {
      const float* Sn = states + (size_t)bn * 320;
      Xn = x[(size_t)bn * 64 + lane];
      N0 = Sn[0 * 64 + lane];
      N1 = Sn[1 * 64 + lane];
      N2 = Sn[2 * 64 + lane];
      N3 = Sn[3 * 64 + lane];
      N4 = Sn[4 * 64 + lane];
    }

    // ---- iteration-start aggregates ----
    const float Yt = wr0 * M0 + wr1 * M1 + wr2 * M2 + wr3 * M3 + wr4 * M4;
    const float S0 = w20 * M0 + w21 * M1 + w22 * M2 + w23 * M3 + w24 * M4;

    // ---- stage A: 5 independent half-transforms (V = A Q^T, transposed) ----
    bX[lane] = X;
    bY[lane] = Yt;
    bS[lane] = S0;
    LGKM0();
    {
      float4 xr0 = *(const float4*)(bX + i * 8);
      float4 xr1 = *(const float4*)(bX + i * 8 + 4);
      float4 yr0 = *(const float4*)(bY + i * 8);
      float4 yr1 = *(const float4*)(bY + i * 8 + 4);
      float4 sr0 = *(const float4*)(bS + i * 8);
      float4 sr1 = *(const float4*)(bS + i * 8 + 4);
      float vXT = dot8(xr0, xr1, Qtj0, Qtj1);
      float vX2 = dot8(xr0, xr1, Q2j0, Q2j1);
      float vY1 = dot8(yr0, yr1, Q1j0, Q1j1);
      float vY3 = dot8(yr0, yr1, Q3j0, Q3j1);
      float vSY = dot8(sr0, sr1, Qyj0, Qyj1);
      const int tr = j * 8 + i;  // transposed store
      bX[tr] = vXT;
      bY[tr] = vY1;
      bS[tr] = vSY;
      b3[tr] = vX2;
      b4[tr] = vY3;
    }
    LGKM0();
    // ---- stage B: C = Q V^T (row j of transposed buffers) ----
    float XT, X2, Y1, Y3, SY;
    {
      float4 c0, c1;
      c0 = *(const float4*)(bX + j * 8); c1 = *(const float4*)(bX + j * 8 + 4);
      XT = dot8(c0, c1, Qti0, Qti1);
      c0 = *(const float4*)(bY + j * 8); c1 = *(const float4*)(bY + j * 8 + 4);
      Y1 = dot8(c0, c1, Q1i0, Q1i1);
      c0 = *(const float4*)(bS + j * 8); c1 = *(const float4*)(bS + j * 8 + 4);
      SY = dot8(c0, c1, Qyi0, Qyi1);
      c0 = *(const float4*)(b3 + j * 8); c1 = *(const float4*)(b3 + j * 8 + 4);
      X2 = dot8(c0, c1, Q2i0, Q2i1);
      c0 = *(const float4*)(b4 + j * 8); c1 = *(const float4*)(b4 + j * 8 + 4);
      Y3 = dot8(c0, c1, Q3i0, Q3i1);
    }

    const float Ot = SY + X2 + Y3;     // Qy S0 Qy^T + c(1-t) QyQtXQt'Qy' + ct ...
    if (b < B) out[(size_t)b * 64 + lane] = Ot;

    const float Ph = XT + Y1;          // (1-t) Qt X Qt^T + t Q1 Yt Q1^T
    M0 = (1.0f - 0.01f) * M0 + 0.01f * Ph;
    M1 = (1.0f - 0.25f) * M1 + 0.25f * Ph;
    M2 = (1.0f - 0.5f)  * M2 + 0.5f  * Ph;
    M3 = (1.0f - 0.9f)  * M3 + 0.9f  * Ph;
    M4 = (1.0f - 0.99f) * M4 + 0.99f * Ph;

    if (b < B) {
      float* SO = out_state + (size_t)b * 320;
      SO[0 * 64 + lane] = M0;
      SO[1 * 64 + lane] = M1;
      SO[2 * 64 + lane] = M2;
      SO[3 * 64 + lane] = M3;
      SO[4 * 64 + lane] = M4;
    }

    // rotate prefetched element in
    X = Xn; M0 = N0; M1 = N1; M2 = N2; M3 = N3; M4 = N4;
    b = bn;
  }
}

extern "C" void kernel_launch(void* const* d_in, const int* in_sizes, int n_in,
                              void* d_out, int out_size, void* d_ws, size_t ws_size,
                              hipStream_t stream) {
  const float* x          = (const float*)d_in[0];
  const float* states     = (const float*)d_in[1];
  const float* kernel_r   = (const float*)d_in[2];
  const float* kernel_t   = (const float*)d_in[3];
  const float* kernel_phi = (const float*)d_in[4];
  const float* kernel_s   = (const float*)d_in[5];
  const float* bias_r     = (const float*)d_in[6];
  const float* bias_t     = (const float*)d_in[7];
  const float* bias_y     = (const float*)d_in[8];
  float* ws = (float*)d_ws;
  float* out = (float*)d_out;

  const int B = in_sizes[0] / 64;
  float* out_state = out + (size_t)B * 64;

  precompute_kernel<<<1, 64, 0, stream>>>(kernel_r, kernel_t, kernel_phi, kernel_s,
                                          bias_r, bias_t, bias_y, ws);

  const int blocks = 2048;           // 8192 waves; B=262144 -> 32 elements/wave
  const int W = blocks * 4;          // waves in grid
  const int ITER = (B + W - 1) / W;
  spdsru_kernel<<<blocks, 256, 0, stream>>>(x, states, ws, out, out_state, B, ITER, W);
}